// Round 3
// baseline (183.137 us; speedup 1.0000x reference)
//
#include <hip/hip_runtime.h>
#include <hip/hip_bf16.h>

#define B_DIM  8192
#define IN_DIM 1024
#define H_DIM  1024
#define K_DIM  2048   // IN + H
#define NT     (K_DIM / 64)

typedef __attribute__((ext_vector_type(8))) short bf16x8;
typedef __attribute__((ext_vector_type(4))) float f32x4;

__device__ __forceinline__ void mfma_16x16x32_bf16(f32x4& d, const bf16x8& a, const bf16x8& b) {
  asm("v_mfma_f32_16x16x32_bf16 %0, %1, %2, %0" : "+v"(d) : "v"(a), "v"(b));
}

__device__ __forceinline__ void gload16(const void* g, void* l) {
  __builtin_amdgcn_global_load_lds(
      (const __attribute__((address_space(1))) void*)g,
      (__attribute__((address_space(3))) void*)l,
      16, 0, 0);
}

__device__ __forceinline__ float fast_sigmoid(float x) {
  return 1.0f / (1.0f + __expf(-x));
}
__device__ __forceinline__ float fast_tanh(float x) {
  float e = __expf(2.0f * x);
  return 1.0f - 2.0f / (e + 1.0f);
}

// ---------------- pack kernels (unchanged, proven) -------------------------
__global__ __launch_bounds__(256) void pack_a_kernel(
    const float* __restrict__ x, const float* __restrict__ hx,
    __hip_bfloat16* __restrict__ A) {
  const int idx = blockIdx.x * 256 + threadIdx.x;
  const int r  = idx >> 8;
  const int kk = (idx & 255) << 3;
  const float* src = (kk < IN_DIM) ? (x + (size_t)r * IN_DIM + kk)
                                   : (hx + (size_t)r * H_DIM + (kk - IN_DIM));
  const float4 v0 = ((const float4*)src)[0];
  const float4 v1 = ((const float4*)src)[1];
  __hip_bfloat16 t[8];
  t[0] = __float2bfloat16(v0.x); t[1] = __float2bfloat16(v0.y);
  t[2] = __float2bfloat16(v0.z); t[3] = __float2bfloat16(v0.w);
  t[4] = __float2bfloat16(v1.x); t[5] = __float2bfloat16(v1.y);
  t[6] = __float2bfloat16(v1.z); t[7] = __float2bfloat16(v1.w);
  *(uint4*)(A + ((size_t)idx << 3)) = *(const uint4*)t;
}

__global__ __launch_bounds__(256) void pack_w_kernel(
    const float* __restrict__ wxi, const float* __restrict__ wxf,
    const float* __restrict__ wxc, const float* __restrict__ wxo,
    const float* __restrict__ whi, const float* __restrict__ whf,
    const float* __restrict__ whc, const float* __restrict__ who,
    __hip_bfloat16* __restrict__ W) {
  const int idx = blockIdx.x * 256 + threadIdx.x;
  const int row = idx >> 8;
  const int kk  = (idx & 255) << 3;
  const int g = row >> 10, n = row & 1023;
  const float* src;
  if (kk < IN_DIM) {
    const float* p = (g == 0) ? wxi : (g == 1) ? wxf : (g == 2) ? wxc : wxo;
    src = p + (size_t)n * IN_DIM + kk;
  } else {
    const float* p = (g == 0) ? whi : (g == 1) ? whf : (g == 2) ? whc : who;
    src = p + (size_t)n * H_DIM + (kk - IN_DIM);
  }
  const float4 v0 = ((const float4*)src)[0];
  const float4 v1 = ((const float4*)src)[1];
  __hip_bfloat16 t[8];
  t[0] = __float2bfloat16(v0.x); t[1] = __float2bfloat16(v0.y);
  t[2] = __float2bfloat16(v0.z); t[3] = __float2bfloat16(v0.w);
  t[4] = __float2bfloat16(v1.x); t[5] = __float2bfloat16(v1.y);
  t[6] = __float2bfloat16(v1.z); t[7] = __float2bfloat16(v1.w);
  *(uint4*)(W + ((size_t)idx << 3)) = *(const uint4*)t;
}

// ---------------- fused GEMM + LSTM epilogue: 4-phase, deep prefetch -------
// Block 512 thr (8 waves, 2M x 4N). Tile: 256 rows x (64 h x 4 gates). BK=64.
// LDS 128 KiB: sA[2][256][64] + sW[2][4][64][64], double-buffered by parity.
// Schedule per K-tile t (buffer p = t&1), staging tile t+1 -> buffer q:
//   ph0: ISSUE A-halves(t+1) [4 ld]; vmcnt(4) [drain tile-t's 8]; barrier;
//        read A-lo + W-lo; 16 MFMA (m-lo, g-lo); barrier
//   ph1: ISSUE W-halves(t+1) [4 ld]; read W-hi; 16 MFMA (m-lo, g-hi); barrier
//   ph2: read A-hi;                 16 MFMA (m-hi, g-hi); barrier
//   ph3: re-read W-lo;              16 MFMA (m-hi, g-lo); barrier
// Issue->drain distance = 3-4 phases (~2000 cyc) >> HBM latency.
// Safety: buf-q writes issued only after ph3(t-1)'s barrier (all buf-q reads
// were issued before it); buf-p reads only after ph0's vmcnt+barrier.
// Chunk-XOR swizzle (proven R1/R2): LDS row holds global chunk c at c^(row&7),
// via pre-swizzled per-lane GLOBAL source; ds_read applies the same XOR.

template<int MH>
__device__ __forceinline__ void load_af(const __hip_bfloat16 (*sAp)[64],
                                        bf16x8 (&af)[4][2], int arowbase,
                                        int chk0, int chk1) {
#pragma unroll
  for (int m = 0; m < 4; ++m) {
    const int row = arowbase + (MH * 4 + m) * 16;
    af[m][0] = *(const bf16x8*)&sAp[row][chk0];
    af[m][1] = *(const bf16x8*)&sAp[row][chk1];
  }
}

template<int GH>
__device__ __forceinline__ void load_bf(const __hip_bfloat16 (*sWp)[64][64],
                                        bf16x8 (&bf)[2][2], int wrow,
                                        int chk0, int chk1) {
#pragma unroll
  for (int gi = 0; gi < 2; ++gi) {
    bf[gi][0] = *(const bf16x8*)&sWp[GH * 2 + gi][wrow][chk0];
    bf[gi][1] = *(const bf16x8*)&sWp[GH * 2 + gi][wrow][chk1];
  }
}

template<int MH, int GH>
__device__ __forceinline__ void mfma16(f32x4 (&acc)[4][8],
                                       const bf16x8 (&af)[4][2],
                                       const bf16x8 (&bf)[2][2]) {
  __builtin_amdgcn_s_setprio(1);
#pragma unroll
  for (int gi = 0; gi < 2; ++gi)
#pragma unroll
    for (int m = 0; m < 4; ++m) {
      mfma_16x16x32_bf16(acc[GH * 2 + gi][MH * 4 + m], af[m][0], bf[gi][0]);
      mfma_16x16x32_bf16(acc[GH * 2 + gi][MH * 4 + m], af[m][1], bf[gi][1]);
    }
  __builtin_amdgcn_s_setprio(0);
}

__global__ __launch_bounds__(512, 2) void lstm_gemm_kernel(
    const __hip_bfloat16* __restrict__ A,   // [8192][2048]
    const __hip_bfloat16* __restrict__ W,   // [4096][2048] gate-major
    const float* __restrict__ cx,
    const float* __restrict__ bxi, const float* __restrict__ bhi,
    const float* __restrict__ bxf, const float* __restrict__ bhf,
    const float* __restrict__ bxc, const float* __restrict__ bhc,
    const float* __restrict__ bxo, const float* __restrict__ bho,
    float* __restrict__ hy, float* __restrict__ cy) {

  __shared__ __align__(16) __hip_bfloat16 sA[2][256][64];
  __shared__ __align__(16) __hip_bfloat16 sW[2][4][64][64];

  const int tid  = threadIdx.x;
  const int w    = tid >> 6;
  const int lane = tid & 63;
  const int wm = w >> 2, wn = w & 3;
  const int lq = lane >> 4, lr16 = lane & 15;

  // XCD-aware bijective swizzle (512 % 8 == 0)
  const int bid = blockIdx.x;
  const int swz = (bid & 7) * 64 + (bid >> 3);
  const int row0 = (swz >> 4) * 256;
  const int col0 = (swz & 15) * 64;

  // staging: thread covers (row-in-64-row-unit = tid>>3, chunk = tid&7)
  const int srow = tid >> 3;
  const int scs  = (tid & 7) ^ (srow & 7);
  const __hip_bfloat16* Asrc = A + (size_t)(row0 + srow) * K_DIM + scs * 8;
  const __hip_bfloat16* Wsrc = W + (size_t)(col0 + srow) * K_DIM + scs * 8;
  const size_t Wg = (size_t)H_DIM * K_DIM;

  // ds_read chunk offsets (elements): ((ks*4+lq) ^ (lr16&7)) * 8
  const int chk0 = ((lq)     ^ (lr16 & 7)) * 8;
  const int chk1 = ((4 + lq) ^ (lr16 & 7)) * 8;
  const int arowbase = wm * 128 + lr16;
  const int wrow = wn * 16 + lr16;

  f32x4 acc[4][8];
#pragma unroll
  for (int g = 0; g < 4; ++g)
#pragma unroll
    for (int m = 0; m < 8; ++m)
      acc[g][m] = (f32x4){0.f, 0.f, 0.f, 0.f};

#define ISSUE_A4(P, KT)                                                        \
  {                                                                            \
    const size_t kof = (size_t)(KT) * 64;                                      \
    gload16(Asrc + (size_t)0 * 64 * K_DIM + kof, (char*)&sA[P][0][0]   + tid * 16); \
    gload16(Asrc + (size_t)1 * 64 * K_DIM + kof, (char*)&sA[P][64][0]  + tid * 16); \
    gload16(Asrc + (size_t)2 * 64 * K_DIM + kof, (char*)&sA[P][128][0] + tid * 16); \
    gload16(Asrc + (size_t)3 * 64 * K_DIM + kof, (char*)&sA[P][192][0] + tid * 16); \
  }
#define ISSUE_W4(P, KT)                                                        \
  {                                                                            \
    const size_t kof = (size_t)(KT) * 64;                                      \
    gload16(Wsrc + (size_t)0 * Wg + kof, (char*)&sW[P][0][0][0] + tid * 16);   \
    gload16(Wsrc + (size_t)1 * Wg + kof, (char*)&sW[P][1][0][0] + tid * 16);   \
    gload16(Wsrc + (size_t)2 * Wg + kof, (char*)&sW[P][2][0][0] + tid * 16);   \
    gload16(Wsrc + (size_t)3 * Wg + kof, (char*)&sW[P][3][0][0] + tid * 16);   \
  }

  // prologue: stage tile 0 -> buf 0 (8 loads outstanding)
  ISSUE_A4(0, 0);
  ISSUE_W4(0, 0);

  bf16x8 af[4][2];
  bf16x8 bf[2][2];

  for (int t = 0; t < NT; ++t) {
    const int p = t & 1, q = p ^ 1;
    const int tn = (t + 1 < NT) ? t + 1 : NT - 1;  // clamp: uniform vmcnt
    const __hip_bfloat16(*sAp)[64] = sA[p];
    const __hip_bfloat16(*sWp)[64][64] = sW[p];

    // ---- ph0: (m-lo, g-lo) ----
    ISSUE_A4(q, tn);   // 12 outstanding; drain previous tile's 8, keep these 4
    asm volatile("s_waitcnt vmcnt(4)\n\ts_barrier" ::: "memory");
    load_af<0>(sAp, af, arowbase, chk0, chk1);
    load_bf<0>(sWp, bf, wrow, chk0, chk1);
    mfma16<0, 0>(acc, af, bf);
    __builtin_amdgcn_s_barrier();

    // ---- ph1: (m-lo, g-hi) ----
    ISSUE_W4(q, tn);   // 8 outstanding through ph1-ph3
    load_bf<1>(sWp, bf, wrow, chk0, chk1);
    mfma16<0, 1>(acc, af, bf);
    __builtin_amdgcn_s_barrier();

    // ---- ph2: (m-hi, g-hi) ----
    load_af<1>(sAp, af, arowbase, chk0, chk1);
    mfma16<1, 1>(acc, af, bf);
    __builtin_amdgcn_s_barrier();

    // ---- ph3: (m-hi, g-lo) ----
    load_bf<0>(sWp, bf, wrow, chk0, chk1);
    mfma16<1, 0>(acc, af, bf);
    __builtin_amdgcn_s_barrier();
  }

  // ---- epilogue: gates + cell update ----
  const int h = col0 + wrow;
  const float bi = bxi[h] + bhi[h];
  const float bff = bxf[h] + bhf[h];
  const float bc = bxc[h] + bhc[h];
  const float bo = bxo[h] + bho[h];
#pragma unroll
  for (int m = 0; m < 8; ++m) {
#pragma unroll
    for (int j = 0; j < 4; ++j) {
      const int r = row0 + wm * 128 + m * 16 + lq * 4 + j;
      const size_t o = (size_t)r * H_DIM + h;
      const float ig = fast_sigmoid(acc[0][m][j] + bi);
      const float fg = fast_sigmoid(acc[1][m][j] + bff);
      const float gg = fast_tanh   (acc[2][m][j] + bc);
      const float og = fast_sigmoid(acc[3][m][j] + bo);
      const float c  = cx[o] * fg + ig * gg;
      cy[o] = c;
      hy[o] = og * fast_tanh(c);
    }
  }
#undef ISSUE_A4
#undef ISSUE_W4
}

extern "C" void kernel_launch(void* const* d_in, const int* in_sizes, int n_in,
                              void* d_out, int out_size, void* d_ws, size_t ws_size,
                              hipStream_t stream) {
  const float* x   = (const float*)d_in[0];
  const float* hx  = (const float*)d_in[1];
  const float* cx  = (const float*)d_in[2];
  const float* wxi = (const float*)d_in[4];  const float* bxi = (const float*)d_in[5];
  const float* wxf = (const float*)d_in[6];  const float* bxf = (const float*)d_in[7];
  const float* wxc = (const float*)d_in[8];  const float* bxc = (const float*)d_in[9];
  const float* wxo = (const float*)d_in[10]; const float* bxo = (const float*)d_in[11];
  const float* whi = (const float*)d_in[12]; const float* bhi = (const float*)d_in[13];
  const float* whf = (const float*)d_in[14]; const float* bhf = (const float*)d_in[15];
  const float* whc = (const float*)d_in[16]; const float* bhc = (const float*)d_in[17];
  const float* who = (const float*)d_in[18]; const float* bho = (const float*)d_in[19];

  __hip_bfloat16* Abf = (__hip_bfloat16*)d_ws;
  __hip_bfloat16* Wbf = (__hip_bfloat16*)((char*)d_ws + (size_t)B_DIM * K_DIM * 2);

  float* hy  = (float*)d_out;
  float* cyo = (float*)d_out + (size_t)B_DIM * H_DIM;

  pack_a_kernel<<<(B_DIM * K_DIM / 8) / 256, 256, 0, stream>>>(x, hx, Abf);
  pack_w_kernel<<<(4 * H_DIM * K_DIM / 8) / 256, 256, 0, stream>>>(
      wxi, wxf, wxc, wxo, whi, whf, whc, who, Wbf);

  lstm_gemm_kernel<<<dim3(512), 512, 0, stream>>>(
      Abf, Wbf, cx, bxi, bhi, bxf, bhf, bxc, bhc, bxo, bho, hy, cyo);
}

// Round 4
// 180.613 us; speedup vs baseline: 1.0140x; 1.0140x over previous
//
#include <hip/hip_runtime.h>
#include <hip/hip_bf16.h>

#define B_DIM  8192
#define IN_DIM 1024
#define H_DIM  1024
#define K_DIM  2048   // IN + H
#define BK     32
#define NT     (K_DIM / BK)   // 64

typedef __attribute__((ext_vector_type(8))) short bf16x8;
typedef __attribute__((ext_vector_type(4))) float f32x4;

__device__ __forceinline__ void mfma_16x16x32_bf16(f32x4& d, const bf16x8& a, const bf16x8& b) {
  asm("v_mfma_f32_16x16x32_bf16 %0, %1, %2, %0" : "+v"(d) : "v"(a), "v"(b));
}

__device__ __forceinline__ void gload16(const void* g, void* l) {
  __builtin_amdgcn_global_load_lds(
      (const __attribute__((address_space(1))) void*)g,
      (__attribute__((address_space(3))) void*)l,
      16, 0, 0);
}

__device__ __forceinline__ float fast_sigmoid(float x) {
  return 1.0f / (1.0f + __expf(-x));
}
__device__ __forceinline__ float fast_tanh(float x) {
  float e = __expf(2.0f * x);
  return 1.0f - 2.0f / (e + 1.0f);
}

// ---------------- pack kernels (unchanged, proven) -------------------------
__global__ __launch_bounds__(256) void pack_a_kernel(
    const float* __restrict__ x, const float* __restrict__ hx,
    __hip_bfloat16* __restrict__ A) {
  const int idx = blockIdx.x * 256 + threadIdx.x;
  const int r  = idx >> 8;
  const int kk = (idx & 255) << 3;
  const float* src = (kk < IN_DIM) ? (x + (size_t)r * IN_DIM + kk)
                                   : (hx + (size_t)r * H_DIM + (kk - IN_DIM));
  const float4 v0 = ((const float4*)src)[0];
  const float4 v1 = ((const float4*)src)[1];
  __hip_bfloat16 t[8];
  t[0] = __float2bfloat16(v0.x); t[1] = __float2bfloat16(v0.y);
  t[2] = __float2bfloat16(v0.z); t[3] = __float2bfloat16(v0.w);
  t[4] = __float2bfloat16(v1.x); t[5] = __float2bfloat16(v1.y);
  t[6] = __float2bfloat16(v1.z); t[7] = __float2bfloat16(v1.w);
  *(uint4*)(A + ((size_t)idx << 3)) = *(const uint4*)t;
}

__global__ __launch_bounds__(256) void pack_w_kernel(
    const float* __restrict__ wxi, const float* __restrict__ wxf,
    const float* __restrict__ wxc, const float* __restrict__ wxo,
    const float* __restrict__ whi, const float* __restrict__ whf,
    const float* __restrict__ whc, const float* __restrict__ who,
    __hip_bfloat16* __restrict__ W) {
  const int idx = blockIdx.x * 256 + threadIdx.x;
  const int row = idx >> 8;
  const int kk  = (idx & 255) << 3;
  const int g = row >> 10, n = row & 1023;
  const float* src;
  if (kk < IN_DIM) {
    const float* p = (g == 0) ? wxi : (g == 1) ? wxf : (g == 2) ? wxc : wxo;
    src = p + (size_t)n * IN_DIM + kk;
  } else {
    const float* p = (g == 0) ? whi : (g == 1) ? whf : (g == 2) ? whc : who;
    src = p + (size_t)n * H_DIM + (kk - IN_DIM);
  }
  const float4 v0 = ((const float4*)src)[0];
  const float4 v1 = ((const float4*)src)[1];
  __hip_bfloat16 t[8];
  t[0] = __float2bfloat16(v0.x); t[1] = __float2bfloat16(v0.y);
  t[2] = __float2bfloat16(v0.z); t[3] = __float2bfloat16(v0.w);
  t[4] = __float2bfloat16(v1.x); t[5] = __float2bfloat16(v1.y);
  t[6] = __float2bfloat16(v1.z); t[7] = __float2bfloat16(v1.w);
  *(uint4*)(W + ((size_t)idx << 3)) = *(const uint4*)t;
}

// ------ fused GEMM + LSTM epilogue: R1 geometry + true 2-phase dbuf --------
// Block 256 thr (4 waves, 2x2). Tile: 128 rows x 64 h x 4 gates. BK=32.
// LDS 48 KiB: 2 bufs x (A[128][32] 8KB + W[256][32] 16KB) -> >=2 blocks/CU TLP.
// BK=32 => 64B LDS rows => naturally bank-uniform b128 reads (no swizzle).
// Per K-tile: STAGE(t+1)[6 gloads/wave]; vmcnt(6)+barrier (t landed, t+1 in
// flight ~1 full iteration); 12 ds_read + 32 MFMA; raw barrier (read-before-
// overwrite; MFMA consumption guarantees reads completed before arrival).
__global__ __launch_bounds__(256, 2) void lstm_gemm_kernel(
    const __hip_bfloat16* __restrict__ A,   // [8192][2048]
    const __hip_bfloat16* __restrict__ W,   // [4096][2048] gate-major
    const float* __restrict__ cx,
    const float* __restrict__ bxi, const float* __restrict__ bhi,
    const float* __restrict__ bxf, const float* __restrict__ bhf,
    const float* __restrict__ bxc, const float* __restrict__ bhc,
    const float* __restrict__ bxo, const float* __restrict__ bho,
    float* __restrict__ hy, float* __restrict__ cy) {

  __shared__ __align__(16) char lds[2][24 * 1024];   // [buf][A 8KB | W 16KB]

  const int tid  = threadIdx.x;
  const int w    = tid >> 6;
  const int lane = tid & 63;
  const int wm = w >> 1, wn = w & 1;
  const int lq = lane >> 4, lr16 = lane & 15;

  // XCD-chunked swizzle: xcd = bid&7 owns row-band of 8 tiles, sweeps cols.
  const int bid = blockIdx.x;                       // 0..1023
  const int row_tile = ((bid & 7) << 3) | ((bid >> 3) & 7);   // 0..63
  const int col_tile = bid >> 6;                              // 0..15
  const int row0 = row_tile * 128;
  const int col0 = col_tile * 64;

  // staging lane geometry: lane -> (row-in-16-row-seg, 16B chunk)
  const int srow = lane >> 2;      // 0..15
  const int schk = lane & 3;       // 0..3

  // per-wave segments: seg = w*6 + s, s=0..5; segs 0..7 = A, 8..23 = W
  const __hip_bfloat16* gsrc[6];
  int ldsoff[6];
#pragma unroll
  for (int s = 0; s < 6; ++s) {
    const int seg = w * 6 + s;
    if (seg < 8) {
      gsrc[s] = A + (size_t)(row0 + seg * 16 + srow) * K_DIM + schk * 8;
    } else {
      const int flat = (seg - 8) * 16 + srow;       // 0..255
      const int g = flat >> 6, n = flat & 63;
      gsrc[s] = W + (size_t)((g << 10) + col0 + n) * K_DIM + schk * 8;
    }
    ldsoff[s] = seg * 1024;
  }

#define STAGE(Q, KT)                                                          \
  {                                                                           \
    const int koff = (KT) * BK;                                               \
    _Pragma("unroll")                                                         \
    for (int s = 0; s < 6; ++s)                                               \
      gload16(gsrc[s] + koff, &lds[Q][ldsoff[s]]);                            \
  }

  f32x4 acc[4][4][2];
#pragma unroll
  for (int g = 0; g < 4; ++g)
#pragma unroll
    for (int m = 0; m < 4; ++m)
#pragma unroll
      for (int nf = 0; nf < 2; ++nf)
        acc[g][m][nf] = (f32x4){0.f, 0.f, 0.f, 0.f};

  // A-frag / W-frag LDS byte offsets (64B rows, k-chunk lq)
  const int aoff = (wm * 64 + lr16) * 64 + lq * 16;          // + m*16*64
  const int woff = 8192 + (wn * 32 + lr16) * 64 + lq * 16;   // + g*64*64 + nf*16*64

  // prologue: stage tile 0 -> buf 0 (6 loads in flight)
  STAGE(0, 0);

  for (int t = 0; t < NT; ++t) {
    const int p = t & 1, q = p ^ 1;
    const int tn = (t + 1 < NT) ? t + 1 : NT - 1;   // clamp: uniform counts

    STAGE(q, tn);   // 12 outstanding max
    asm volatile("s_waitcnt vmcnt(6)\n\ts_barrier" ::: "memory");

    const char* base = lds[p];
    bf16x8 af[4];
#pragma unroll
    for (int m = 0; m < 4; ++m)
      af[m] = *(const bf16x8*)(base + aoff + m * (16 * 64));

    __builtin_amdgcn_s_setprio(1);
#pragma unroll
    for (int g = 0; g < 4; ++g) {
      const char* wb = base + woff + g * (64 * 64);
      const bf16x8 b0 = *(const bf16x8*)(wb);
      const bf16x8 b1 = *(const bf16x8*)(wb + 16 * 64);
#pragma unroll
      for (int m = 0; m < 4; ++m) {
        mfma_16x16x32_bf16(acc[g][m][0], af[m], b0);
        mfma_16x16x32_bf16(acc[g][m][1], af[m], b1);
      }
    }
    __builtin_amdgcn_s_setprio(0);

    asm volatile("s_barrier" ::: "memory");   // reads done before overwrite
  }

  // drain: no DMA may land after this block's LDS is recycled
  asm volatile("s_waitcnt vmcnt(0)" ::: "memory");

  // ---- epilogue: gates + cell update ----
  const int h = col0 + wn * 32 + lr16;   // nf adds 16
#pragma unroll
  for (int nf = 0; nf < 2; ++nf) {
    const int hh = h + nf * 16;
    const float bi = bxi[hh] + bhi[hh];
    const float bff = bxf[hh] + bhf[hh];
    const float bc = bxc[hh] + bhc[hh];
    const float bo = bxo[hh] + bho[hh];
#pragma unroll
    for (int m = 0; m < 4; ++m) {
#pragma unroll
      for (int j = 0; j < 4; ++j) {
        const int r = row0 + wm * 64 + m * 16 + lq * 4 + j;
        const size_t o = (size_t)r * H_DIM + hh;
        const float ig = fast_sigmoid(acc[0][m][nf][j] + bi);
        const float fg = fast_sigmoid(acc[1][m][nf][j] + bff);
        const float gg = fast_tanh   (acc[2][m][nf][j] + bc);
        const float og = fast_sigmoid(acc[3][m][nf][j] + bo);
        const float c  = cx[o] * fg + ig * gg;
        cy[o] = c;
        hy[o] = og * fast_tanh(c);
      }
    }
  }
#undef STAGE
}

extern "C" void kernel_launch(void* const* d_in, const int* in_sizes, int n_in,
                              void* d_out, int out_size, void* d_ws, size_t ws_size,
                              hipStream_t stream) {
  const float* x   = (const float*)d_in[0];
  const float* hx  = (const float*)d_in[1];
  const float* cx  = (const float*)d_in[2];
  const float* wxi = (const float*)d_in[4];  const float* bxi = (const float*)d_in[5];
  const float* wxf = (const float*)d_in[6];  const float* bxf = (const float*)d_in[7];
  const float* wxc = (const float*)d_in[8];  const float* bxc = (const float*)d_in[9];
  const float* wxo = (const float*)d_in[10]; const float* bxo = (const float*)d_in[11];
  const float* whi = (const float*)d_in[12]; const float* bhi = (const float*)d_in[13];
  const float* whf = (const float*)d_in[14]; const float* bhf = (const float*)d_in[15];
  const float* whc = (const float*)d_in[16]; const float* bhc = (const float*)d_in[17];
  const float* who = (const float*)d_in[18]; const float* bho = (const float*)d_in[19];

  __hip_bfloat16* Abf = (__hip_bfloat16*)d_ws;
  __hip_bfloat16* Wbf = (__hip_bfloat16*)((char*)d_ws + (size_t)B_DIM * K_DIM * 2);

  float* hy  = (float*)d_out;
  float* cyo = (float*)d_out + (size_t)B_DIM * H_DIM;

  pack_a_kernel<<<(B_DIM * K_DIM / 8) / 256, 256, 0, stream>>>(x, hx, Abf);
  pack_w_kernel<<<(4 * H_DIM * K_DIM / 8) / 256, 256, 0, stream>>>(
      wxi, wxf, wxc, wxo, whi, whf, whc, who, Wbf);

  lstm_gemm_kernel<<<dim3(1024), 256, 0, stream>>>(
      Abf, Wbf, cx, bxi, bhi, bxf, bhf, bxc, bhc, bxo, bho, hy, cyo);
}

// Round 5
// 169.841 us; speedup vs baseline: 1.0783x; 1.0634x over previous
//
#include <hip/hip_runtime.h>
#include <hip/hip_bf16.h>

#define B_DIM  8192
#define IN_DIM 1024
#define H_DIM  1024
#define K_DIM  2048   // IN + H
#define BK     64
#define NT     (K_DIM / BK)   // 32

typedef __attribute__((ext_vector_type(8))) short bf16x8;
typedef __attribute__((ext_vector_type(4))) float f32x4;

__device__ __forceinline__ void mfma_16x16x32_bf16(f32x4& d, const bf16x8& a, const bf16x8& b) {
  asm("v_mfma_f32_16x16x32_bf16 %0, %1, %2, %0" : "+v"(d) : "v"(a), "v"(b));
}

__device__ __forceinline__ void gload16(const void* g, void* l) {
  __builtin_amdgcn_global_load_lds(
      (const __attribute__((address_space(1))) void*)g,
      (__attribute__((address_space(3))) void*)l,
      16, 0, 0);
}

__device__ __forceinline__ float fast_sigmoid(float x) {
  return 1.0f / (1.0f + __expf(-x));
}
__device__ __forceinline__ float fast_tanh(float x) {
  float e = __expf(2.0f * x);
  return 1.0f - 2.0f / (e + 1.0f);
}

// ---------------- pack kernels (unchanged, proven) -------------------------
__global__ __launch_bounds__(256) void pack_a_kernel(
    const float* __restrict__ x, const float* __restrict__ hx,
    __hip_bfloat16* __restrict__ A) {
  const int idx = blockIdx.x * 256 + threadIdx.x;
  const int r  = idx >> 8;
  const int kk = (idx & 255) << 3;
  const float* src = (kk < IN_DIM) ? (x + (size_t)r * IN_DIM + kk)
                                   : (hx + (size_t)r * H_DIM + (kk - IN_DIM));
  const float4 v0 = ((const float4*)src)[0];
  const float4 v1 = ((const float4*)src)[1];
  __hip_bfloat16 t[8];
  t[0] = __float2bfloat16(v0.x); t[1] = __float2bfloat16(v0.y);
  t[2] = __float2bfloat16(v0.z); t[3] = __float2bfloat16(v0.w);
  t[4] = __float2bfloat16(v1.x); t[5] = __float2bfloat16(v1.y);
  t[6] = __float2bfloat16(v1.z); t[7] = __float2bfloat16(v1.w);
  *(uint4*)(A + ((size_t)idx << 3)) = *(const uint4*)t;
}

__global__ __launch_bounds__(256) void pack_w_kernel(
    const float* __restrict__ wxi, const float* __restrict__ wxf,
    const float* __restrict__ wxc, const float* __restrict__ wxo,
    const float* __restrict__ whi, const float* __restrict__ whf,
    const float* __restrict__ whc, const float* __restrict__ who,
    __hip_bfloat16* __restrict__ W) {
  const int idx = blockIdx.x * 256 + threadIdx.x;
  const int row = idx >> 8;
  const int kk  = (idx & 255) << 3;
  const int g = row >> 10, n = row & 1023;
  const float* src;
  if (kk < IN_DIM) {
    const float* p = (g == 0) ? wxi : (g == 1) ? wxf : (g == 2) ? wxc : wxo;
    src = p + (size_t)n * IN_DIM + kk;
  } else {
    const float* p = (g == 0) ? whi : (g == 1) ? whf : (g == 2) ? whc : who;
    src = p + (size_t)n * H_DIM + (kk - IN_DIM);
  }
  const float4 v0 = ((const float4*)src)[0];
  const float4 v1 = ((const float4*)src)[1];
  __hip_bfloat16 t[8];
  t[0] = __float2bfloat16(v0.x); t[1] = __float2bfloat16(v0.y);
  t[2] = __float2bfloat16(v0.z); t[3] = __float2bfloat16(v0.w);
  t[4] = __float2bfloat16(v1.x); t[5] = __float2bfloat16(v1.y);
  t[6] = __float2bfloat16(v1.z); t[7] = __float2bfloat16(v1.w);
  *(uint4*)(W + ((size_t)idx << 3)) = *(const uint4*)t;
}

// -------- fused GEMM + LSTM epilogue: 4-phase template, derived invariants --
// Block 512 thr, 8 waves (wm = w>>2 in {0,1} = 128-row half; wn = w&3 = 16-h
// quarter). Tile: 256 rows x 64 h x 4 gates. BK=64. Gates wave-local.
// LDS 128 KiB: lds[2][64KB]; per buf: A0(16K) A1(16K) W(32K: 4 gates x 8K).
// Rows are 128B (64 bf16): chunk-XOR swizzle (R1-proven 0-conflict):
//   content chunk c of row r stored at chunk c^(r&7); achieved by
//   pre-swizzled per-lane GLOBAL source col, linear gload_lds dest.
// Per tile t (read buf p=t&1), phases P1..P4 = (mh,gh) quadrants
// (0,0)(0,1)(1,1)(1,0); W-frags live in regs whole tile (P4: 0 ds_reads).
//   P1: ds_read af(mh0)[8] + wf0[4]; STAGE_W(t+1)->q; BARRIER; 16 MFMA; BARRIER
//   P2: ds_read wf1[4];                               BARRIER; 16 MFMA; BARRIER
//   P3: ds_read af(mh1)[8];                           BARRIER; 16 MFMA; BARRIER
//   P4: STAGE_A(t+2)->p; vmcnt(4)+BARRIER;                     16 MFMA; BARRIER
// Safety (all verified): W of q last read P4(t-1), staged P1(t) after its
// BARRIER-B; A of p last read P3(t) (drained at P3 MFMA), staged P4(t) after
// P3's BARRIER-B. vmcnt(4)@P4 confirms A(t+1) [4-phase flight] and W(t+1)
// [3-phase flight], keeps A(t+2) in flight.
__global__ __launch_bounds__(512, 2) void lstm_gemm_kernel(
    const __hip_bfloat16* __restrict__ A,   // [8192][2048]
    const __hip_bfloat16* __restrict__ W,   // [4096][2048] gate-major
    const float* __restrict__ cx,
    const float* __restrict__ bxi, const float* __restrict__ bhi,
    const float* __restrict__ bxf, const float* __restrict__ bhf,
    const float* __restrict__ bxc, const float* __restrict__ bhc,
    const float* __restrict__ bxo, const float* __restrict__ bho,
    float* __restrict__ hy, float* __restrict__ cy) {

  __shared__ __align__(16) char lds[2][64 * 1024];

  const int tid  = threadIdx.x;
  const int w    = tid >> 6;
  const int lane = tid & 63;
  const int wm = w >> 2, wn = w & 3;
  const int lq = lane >> 4, lr16 = lane & 15;

  // XCD-chunked swizzle: 512 blocks, xcd = bid&7 gets 2 col-tiles x 32 rows.
  const int bid = blockIdx.x;
  const int xcd = bid & 7, idx = bid >> 3;            // idx 0..63
  const int col_tile = xcd * 2 + (idx >> 5);          // 0..15
  const int row_tile = idx & 31;                      // 0..31
  const int row0 = row_tile * 256;
  const int col0 = col_tile * 64;

  // staging: thread -> (row-in-64-row-unit = tid>>3, chunk = tid&7), source
  // chunk pre-swizzled; LDS dest linear tid*16.
  const int srow = tid >> 3;
  const int scs  = (tid & 7) ^ (srow & 7);
  const __hip_bfloat16* Asrc = A + (size_t)(row0 + srow) * K_DIM + scs * 8;
  const __hip_bfloat16* Wsrc = W + (size_t)(col0 + srow) * K_DIM + scs * 8;
  const size_t Wg = (size_t)H_DIM * K_DIM;

  // read offsets (bytes). A frag (MH,m,kc): aoffkc + MH*8192 + m*2048.
  // W frag (g,kc): woffkc + g*8192.
  const int xr = lr16 & 7;
  const int aoff0 = wm * 16384 + lr16 * 128 + ((lq)     ^ xr) * 16;
  const int aoff1 = wm * 16384 + lr16 * 128 + ((4 + lq) ^ xr) * 16;
  const int woff0 = 32768 + (wn * 16 + lr16) * 128 + ((lq)     ^ xr) * 16;
  const int woff1 = 32768 + (wn * 16 + lr16) * 128 + ((4 + lq) ^ xr) * 16;

  f32x4 acc[4][8];
#pragma unroll
  for (int g = 0; g < 4; ++g)
#pragma unroll
    for (int m = 0; m < 8; ++m)
      acc[g][m] = (f32x4){0.f, 0.f, 0.f, 0.f};

#define STAGE_A(Q, KT)                                                        \
  {                                                                           \
    const size_t kof = (size_t)(KT) * BK;                                     \
    gload16(Asrc + kof,                 &lds[Q][tid * 16]);                   \
    gload16(Asrc + 64 * K_DIM + kof,    &lds[Q][8192  + tid * 16]);           \
    gload16(Asrc + 128 * K_DIM + kof,   &lds[Q][16384 + tid * 16]);           \
    gload16(Asrc + 192 * K_DIM + kof,   &lds[Q][24576 + tid * 16]);           \
  }
#define STAGE_W(Q, KT)                                                        \
  {                                                                           \
    const size_t kof = (size_t)(KT) * BK;                                     \
    gload16(Wsrc + kof,          &lds[Q][32768 + tid * 16]);                  \
    gload16(Wsrc + Wg + kof,     &lds[Q][40960 + tid * 16]);                  \
    gload16(Wsrc + 2 * Wg + kof, &lds[Q][49152 + tid * 16]);                  \
    gload16(Wsrc + 3 * Wg + kof, &lds[Q][57344 + tid * 16]);                  \
  }
#define BAR()  asm volatile("s_barrier" ::: "memory")

  // prologue: tile0 -> buf0, A(1) -> buf1; confirm tile0, keep A(1) in flight
  STAGE_A(0, 0);
  STAGE_W(0, 0);
  STAGE_A(1, 1);
  asm volatile("s_waitcnt vmcnt(4)\n\ts_barrier" ::: "memory");

  bf16x8 af[4][2], wf0[2][2], wf1[2][2];

  for (int t = 0; t < NT; ++t) {
    const int p = t & 1, q = p ^ 1;
    const int tn1 = (t + 1 < NT) ? t + 1 : NT - 1;   // clamp keeps counts uniform
    const int tn2 = (t + 2 < NT) ? t + 2 : NT - 1;
    const char* rb = lds[p];

    // ---- P1: (mh0, gates 0-1) ----
#pragma unroll
    for (int m = 0; m < 4; ++m) {
      af[m][0] = *(const bf16x8*)(rb + aoff0 + m * 2048);
      af[m][1] = *(const bf16x8*)(rb + aoff1 + m * 2048);
    }
#pragma unroll
    for (int gi = 0; gi < 2; ++gi) {
      wf0[gi][0] = *(const bf16x8*)(rb + woff0 + gi * 8192);
      wf0[gi][1] = *(const bf16x8*)(rb + woff1 + gi * 8192);
    }
    STAGE_W(q, tn1);
    BAR();
    __builtin_amdgcn_s_setprio(1);
#pragma unroll
    for (int gi = 0; gi < 2; ++gi)
#pragma unroll
      for (int m = 0; m < 4; ++m) {
        mfma_16x16x32_bf16(acc[gi][m], af[m][0], wf0[gi][0]);
        mfma_16x16x32_bf16(acc[gi][m], af[m][1], wf0[gi][1]);
      }
    __builtin_amdgcn_s_setprio(0);
    BAR();

    // ---- P2: (mh0, gates 2-3) ----
#pragma unroll
    for (int gi = 0; gi < 2; ++gi) {
      wf1[gi][0] = *(const bf16x8*)(rb + woff0 + (2 + gi) * 8192);
      wf1[gi][1] = *(const bf16x8*)(rb + woff1 + (2 + gi) * 8192);
    }
    BAR();
    __builtin_amdgcn_s_setprio(1);
#pragma unroll
    for (int gi = 0; gi < 2; ++gi)
#pragma unroll
      for (int m = 0; m < 4; ++m) {
        mfma_16x16x32_bf16(acc[2 + gi][m], af[m][0], wf1[gi][0]);
        mfma_16x16x32_bf16(acc[2 + gi][m], af[m][1], wf1[gi][1]);
      }
    __builtin_amdgcn_s_setprio(0);
    BAR();

    // ---- P3: (mh1, gates 2-3) ----
#pragma unroll
    for (int m = 0; m < 4; ++m) {
      af[m][0] = *(const bf16x8*)(rb + aoff0 + 8192 + m * 2048);
      af[m][1] = *(const bf16x8*)(rb + aoff1 + 8192 + m * 2048);
    }
    BAR();
    __builtin_amdgcn_s_setprio(1);
#pragma unroll
    for (int gi = 0; gi < 2; ++gi)
#pragma unroll
      for (int m = 0; m < 4; ++m) {
        mfma_16x16x32_bf16(acc[2 + gi][4 + m], af[m][0], wf1[gi][0]);
        mfma_16x16x32_bf16(acc[2 + gi][4 + m], af[m][1], wf1[gi][1]);
      }
    __builtin_amdgcn_s_setprio(0);
    BAR();

    // ---- P4: (mh1, gates 0-1); stage A(t+2); single counted vmcnt ----
    STAGE_A(p, tn2);
    asm volatile("s_waitcnt vmcnt(4)\n\ts_barrier" ::: "memory");
    __builtin_amdgcn_s_setprio(1);
#pragma unroll
    for (int gi = 0; gi < 2; ++gi)
#pragma unroll
      for (int m = 0; m < 4; ++m) {
        mfma_16x16x32_bf16(acc[gi][4 + m], af[m][0], wf0[gi][0]);
        mfma_16x16x32_bf16(acc[gi][4 + m], af[m][1], wf0[gi][1]);
      }
    __builtin_amdgcn_s_setprio(0);
    BAR();
  }

  // drain redundant tail DMAs before the block's LDS is recycled
  asm volatile("s_waitcnt vmcnt(0)" ::: "memory");

  // ---- epilogue: gates + cell update (wave-local, all 4 gates in-wave) ----
  const int h = col0 + wn * 16 + lr16;
  const float bi  = bxi[h] + bhi[h];
  const float bff = bxf[h] + bhf[h];
  const float bc  = bxc[h] + bhc[h];
  const float bo  = bxo[h] + bho[h];
#pragma unroll
  for (int m = 0; m < 8; ++m) {
#pragma unroll
    for (int j = 0; j < 4; ++j) {
      const int r = row0 + wm * 128 + m * 16 + lq * 4 + j;
      const size_t o = (size_t)r * H_DIM + h;
      const float ig = fast_sigmoid(acc[0][m][j] + bi);
      const float fg = fast_sigmoid(acc[1][m][j] + bff);
      const float gg = fast_tanh   (acc[2][m][j] + bc);
      const float og = fast_sigmoid(acc[3][m][j] + bo);
      const float c  = cx[o] * fg + ig * gg;
      cy[o] = c;
      hy[o] = og * fast_tanh(c);
    }
  }
#undef STAGE_A
#undef STAGE_W
#undef BAR
}

extern "C" void kernel_launch(void* const* d_in, const int* in_sizes, int n_in,
                              void* d_out, int out_size, void* d_ws, size_t ws_size,
                              hipStream_t stream) {
  const float* x   = (const float*)d_in[0];
  const float* hx  = (const float*)d_in[1];
  const float* cx  = (const float*)d_in[2];
  const float* wxi = (const float*)d_in[4];  const float* bxi = (const float*)d_in[5];
  const float* wxf = (const float*)d_in[6];  const float* bxf = (const float*)d_in[7];
  const float* wxc = (const float*)d_in[8];  const float* bxc = (const float*)d_in[9];
  const float* wxo = (const float*)d_in[10]; const float* bxo = (const float*)d_in[11];
  const float* whi = (const float*)d_in[12]; const float* bhi = (const float*)d_in[13];
  const float* whf = (const float*)d_in[14]; const float* bhf = (const float*)d_in[15];
  const float* whc = (const float*)d_in[16]; const float* bhc = (const float*)d_in[17];
  const float* who = (const float*)d_in[18]; const float* bho = (const float*)d_in[19];

  __hip_bfloat16* Abf = (__hip_bfloat16*)d_ws;
  __hip_bfloat16* Wbf = (__hip_bfloat16*)((char*)d_ws + (size_t)B_DIM * K_DIM * 2);

  float* hy  = (float*)d_out;
  float* cyo = (float*)d_out + (size_t)B_DIM * H_DIM;

  pack_a_kernel<<<(B_DIM * K_DIM / 8) / 256, 256, 0, stream>>>(x, hx, Abf);
  pack_w_kernel<<<(4 * H_DIM * K_DIM / 8) / 256, 256, 0, stream>>>(
      wxi, wxf, wxc, wxo, whi, whf, whc, who, Wbf);

  lstm_gemm_kernel<<<dim3(512), 512, 0, stream>>>(
      Abf, Wbf, cx, bxi, bhi, bxf, bhf, bxc, bhc, bxo, bho, hy, cyo);
}

// Round 6
// 163.846 us; speedup vs baseline: 1.1177x; 1.0366x over previous
//
#include <hip/hip_runtime.h>
#include <hip/hip_bf16.h>

#define B_DIM  8192
#define IN_DIM 1024
#define H_DIM  1024
#define K_DIM  2048   // IN + H
#define BK     64
#define NT     (K_DIM / BK)   // 32

typedef __attribute__((ext_vector_type(8))) short bf16x8;
typedef __attribute__((ext_vector_type(4))) float f32x4;

// volatile: pinned between the volatile barrier asms (phase integrity)
__device__ __forceinline__ void mfma_16x16x32_bf16(f32x4& d, const bf16x8& a, const bf16x8& b) {
  asm volatile("v_mfma_f32_16x16x32_bf16 %0, %1, %2, %0" : "+v"(d) : "v"(a), "v"(b));
}

__device__ __forceinline__ void gload16(const void* g, void* l) {
  __builtin_amdgcn_global_load_lds(
      (const __attribute__((address_space(1))) void*)g,
      (__attribute__((address_space(3))) void*)l,
      16, 0, 0);
}

__device__ __forceinline__ float fast_sigmoid(float x) {
  return 1.0f / (1.0f + __expf(-x));
}
__device__ __forceinline__ float fast_tanh(float x) {
  float e = __expf(2.0f * x);
  return 1.0f - 2.0f / (e + 1.0f);
}

// ---------------- pack kernels (unchanged, proven) -------------------------
__global__ __launch_bounds__(256) void pack_a_kernel(
    const float* __restrict__ x, const float* __restrict__ hx,
    __hip_bfloat16* __restrict__ A) {
  const int idx = blockIdx.x * 256 + threadIdx.x;
  const int r  = idx >> 8;
  const int kk = (idx & 255) << 3;
  const float* src = (kk < IN_DIM) ? (x + (size_t)r * IN_DIM + kk)
                                   : (hx + (size_t)r * H_DIM + (kk - IN_DIM));
  const float4 v0 = ((const float4*)src)[0];
  const float4 v1 = ((const float4*)src)[1];
  __hip_bfloat16 t[8];
  t[0] = __float2bfloat16(v0.x); t[1] = __float2bfloat16(v0.y);
  t[2] = __float2bfloat16(v0.z); t[3] = __float2bfloat16(v0.w);
  t[4] = __float2bfloat16(v1.x); t[5] = __float2bfloat16(v1.y);
  t[6] = __float2bfloat16(v1.z); t[7] = __float2bfloat16(v1.w);
  *(uint4*)(A + ((size_t)idx << 3)) = *(const uint4*)t;
}

__global__ __launch_bounds__(256) void pack_w_kernel(
    const float* __restrict__ wxi, const float* __restrict__ wxf,
    const float* __restrict__ wxc, const float* __restrict__ wxo,
    const float* __restrict__ whi, const float* __restrict__ whf,
    const float* __restrict__ whc, const float* __restrict__ who,
    __hip_bfloat16* __restrict__ W) {
  const int idx = blockIdx.x * 256 + threadIdx.x;
  const int row = idx >> 8;
  const int kk  = (idx & 255) << 3;
  const int g = row >> 10, n = row & 1023;
  const float* src;
  if (kk < IN_DIM) {
    const float* p = (g == 0) ? wxi : (g == 1) ? wxf : (g == 2) ? wxc : wxo;
    src = p + (size_t)n * IN_DIM + kk;
  } else {
    const float* p = (g == 0) ? whi : (g == 1) ? whf : (g == 2) ? whc : who;
    src = p + (size_t)n * H_DIM + (kk - IN_DIM);
  }
  const float4 v0 = ((const float4*)src)[0];
  const float4 v1 = ((const float4*)src)[1];
  __hip_bfloat16 t[8];
  t[0] = __float2bfloat16(v0.x); t[1] = __float2bfloat16(v0.y);
  t[2] = __float2bfloat16(v0.z); t[3] = __float2bfloat16(v0.w);
  t[4] = __float2bfloat16(v1.x); t[5] = __float2bfloat16(v1.y);
  t[6] = __float2bfloat16(v1.z); t[7] = __float2bfloat16(v1.w);
  *(uint4*)(W + ((size_t)idx << 3)) = *(const uint4*)t;
}

// ------ fused GEMM + LSTM epilogue: phase-ahead register pipeline ----------
// Block 512 thr, 8 waves (wm=w>>2 row-half, wn=w&3 h-quarter). Tile 256 rows
// x 64h x 4 gates, BK=64. LDS 128KB = 2 bufs x (A 32KB + W 32KB), 1 block/CU.
// INVARIANT: every phase's MFMA consumes ONLY frags ds_read >=1 phase earlier
// -> wave never stalls on same-phase LDS service; LDS pipe overlaps MFMA pipe.
//   P1: read wf23(t); STAGE A,W(t+1)->q [8 gl]; MFMA Q1=(mh0,g01) [af0,wf01
//       read at P4(t-1) from this buffer]
//   P2: read af1(t) [mh1]; MFMA Q2=(mh0,g23) [wf23 from P1]
//   P3:                    MFMA Q3=(mh1,g01) [af1 from P2]
//   P4: vmcnt(0)+s_barrier [all waves' DMA landed]; read af0,wf01(t+1) from q
//       [regs dead: af0 last use P2, wf01 last use P3]; MFMA Q4=(mh1,g23)
//       [uses neither]; s_barrier.
// Overwrite-safety (2 barriers/tile suffice): STAGE->q(t)=p(t-1) at P1(t):
// that buf's reads (wf23,af1 of t-1) drained by Q4(t-1) before BAR-B(t-1);
// q-reads at P4(t) ordered after q-DMA by fused vmcnt+barrier. Wave slip
// bounded to one barrier interval by s_barrier rendezvous.
// Chunk-XOR swizzle (R1-proven 0-conflict) via pre-swizzled global source.
__global__ __launch_bounds__(512, 2) void lstm_gemm_kernel(
    const __hip_bfloat16* __restrict__ A,   // [8192][2048]
    const __hip_bfloat16* __restrict__ W,   // [4096][2048] gate-major
    const float* __restrict__ cx,
    const float* __restrict__ bxi, const float* __restrict__ bhi,
    const float* __restrict__ bxf, const float* __restrict__ bhf,
    const float* __restrict__ bxc, const float* __restrict__ bhc,
    const float* __restrict__ bxo, const float* __restrict__ bho,
    float* __restrict__ hy, float* __restrict__ cy) {

  __shared__ __align__(16) char lds[2][64 * 1024];  // per buf: A@0, W@32768

  const int tid  = threadIdx.x;
  const int w    = tid >> 6;
  const int lane = tid & 63;
  const int wm = w >> 2, wn = w & 3;
  const int lq = lane >> 4, lr16 = lane & 15;

  // R1-style raster: consecutive blocks share the W panel (L2-resident)
  const int bid = blockIdx.x;                 // 512 blocks
  const int row0 = (bid & 31) * 256;
  const int col0 = (bid >> 5) * 64;

  // staging: thread -> (row-in-64-row-unit tid>>3, chunk tid&7), source chunk
  // pre-swizzled (c ^ row&7); LDS dest linear tid*16.
  const int srow = tid >> 3;
  const int scs  = (tid & 7) ^ (srow & 7);
  const __hip_bfloat16* Asrc = A + (size_t)(row0 + srow) * K_DIM + scs * 8;
  const __hip_bfloat16* Wsrc = W + (size_t)(col0 + srow) * K_DIM + scs * 8;
  const size_t Wg = (size_t)H_DIM * K_DIM;

  // ds_read byte offsets with matching XOR; m adds 2048, mh adds 8192,
  // gate adds 8192 beyond the 32768 W base.
  const int xr = lr16 & 7;
  const int aoff0 = wm * 16384 + lr16 * 128 + ((lq)     ^ xr) * 16;
  const int aoff1 = wm * 16384 + lr16 * 128 + ((4 + lq) ^ xr) * 16;
  const int woff0 = 32768 + (wn * 16 + lr16) * 128 + ((lq)     ^ xr) * 16;
  const int woff1 = 32768 + (wn * 16 + lr16) * 128 + ((4 + lq) ^ xr) * 16;

  f32x4 acc[4][8];
#pragma unroll
  for (int g = 0; g < 4; ++g)
#pragma unroll
    for (int m = 0; m < 8; ++m)
      acc[g][m] = (f32x4){0.f, 0.f, 0.f, 0.f};

#define STAGE_A(Q, KT)                                                        \
  {                                                                           \
    const size_t kof = (size_t)(KT) * BK;                                     \
    gload16(Asrc + kof,               &lds[Q][tid * 16]);                     \
    gload16(Asrc + 64 * K_DIM + kof,  &lds[Q][8192  + tid * 16]);             \
    gload16(Asrc + 128 * K_DIM + kof, &lds[Q][16384 + tid * 16]);             \
    gload16(Asrc + 192 * K_DIM + kof, &lds[Q][24576 + tid * 16]);             \
  }
#define STAGE_W(Q, KT)                                                        \
  {                                                                           \
    const size_t kof = (size_t)(KT) * BK;                                     \
    gload16(Wsrc + kof,          &lds[Q][32768 + tid * 16]);                  \
    gload16(Wsrc + Wg + kof,     &lds[Q][40960 + tid * 16]);                  \
    gload16(Wsrc + 2 * Wg + kof, &lds[Q][49152 + tid * 16]);                  \
    gload16(Wsrc + 3 * Wg + kof, &lds[Q][57344 + tid * 16]);                  \
  }

  // prologue: tile0 -> buf0; confirm landed; preload P1(0)'s operands
  STAGE_A(0, 0);
  STAGE_W(0, 0);
  asm volatile("s_waitcnt vmcnt(0)\n\ts_barrier" ::: "memory");

  bf16x8 af0[4][2], af1[4][2], wf01[2][2], wf23[2][2];
  {
    const char* rb = lds[0];
#pragma unroll
    for (int m = 0; m < 4; ++m) {
      af0[m][0] = *(const bf16x8*)(rb + aoff0 + m * 2048);
      af0[m][1] = *(const bf16x8*)(rb + aoff1 + m * 2048);
    }
#pragma unroll
    for (int gi = 0; gi < 2; ++gi) {
      wf01[gi][0] = *(const bf16x8*)(rb + woff0 + gi * 8192);
      wf01[gi][1] = *(const bf16x8*)(rb + woff1 + gi * 8192);
    }
  }

  for (int t = 0; t < NT; ++t) {
    const int p = t & 1, q = p ^ 1;
    const int tn1 = (t + 1 < NT) ? t + 1 : NT - 1;  // clamp: uniform counts
    const char* rb = lds[p];
    const char* nb = lds[q];

    // ---- P1: read wf23(t); stage tile t+1 -> q; MFMA Q1=(mh0,g01) ----
#pragma unroll
    for (int gi = 0; gi < 2; ++gi) {
      wf23[gi][0] = *(const bf16x8*)(rb + woff0 + (2 + gi) * 8192);
      wf23[gi][1] = *(const bf16x8*)(rb + woff1 + (2 + gi) * 8192);
    }
    STAGE_A(q, tn1);
    STAGE_W(q, tn1);
    __builtin_amdgcn_s_setprio(1);
#pragma unroll
    for (int gi = 0; gi < 2; ++gi)
#pragma unroll
      for (int m = 0; m < 4; ++m) {
        mfma_16x16x32_bf16(acc[gi][m], af0[m][0], wf01[gi][0]);
        mfma_16x16x32_bf16(acc[gi][m], af0[m][1], wf01[gi][1]);
      }
    __builtin_amdgcn_s_setprio(0);

    // ---- P2: read af1(t) [mh1]; MFMA Q2=(mh0,g23) ----
#pragma unroll
    for (int m = 0; m < 4; ++m) {
      af1[m][0] = *(const bf16x8*)(rb + aoff0 + 8192 + m * 2048);
      af1[m][1] = *(const bf16x8*)(rb + aoff1 + 8192 + m * 2048);
    }
    __builtin_amdgcn_s_setprio(1);
#pragma unroll
    for (int gi = 0; gi < 2; ++gi)
#pragma unroll
      for (int m = 0; m < 4; ++m) {
        mfma_16x16x32_bf16(acc[2 + gi][m], af0[m][0], wf23[gi][0]);
        mfma_16x16x32_bf16(acc[2 + gi][m], af0[m][1], wf23[gi][1]);
      }
    __builtin_amdgcn_s_setprio(0);

    // ---- P3: MFMA Q3=(mh1,g01) ----
    __builtin_amdgcn_s_setprio(1);
#pragma unroll
    for (int gi = 0; gi < 2; ++gi)
#pragma unroll
      for (int m = 0; m < 4; ++m) {
        mfma_16x16x32_bf16(acc[gi][4 + m], af1[m][0], wf01[gi][0]);
        mfma_16x16x32_bf16(acc[gi][4 + m], af1[m][1], wf01[gi][1]);
      }
    __builtin_amdgcn_s_setprio(0);

    // ---- P4: all DMA landed; read next tile's af0/wf01 from q; Q4 ----
    asm volatile("s_waitcnt vmcnt(0)\n\ts_barrier" ::: "memory");
#pragma unroll
    for (int m = 0; m < 4; ++m) {
      af0[m][0] = *(const bf16x8*)(nb + aoff0 + m * 2048);
      af0[m][1] = *(const bf16x8*)(nb + aoff1 + m * 2048);
    }
#pragma unroll
    for (int gi = 0; gi < 2; ++gi) {
      wf01[gi][0] = *(const bf16x8*)(nb + woff0 + gi * 8192);
      wf01[gi][1] = *(const bf16x8*)(nb + woff1 + gi * 8192);
    }
    __builtin_amdgcn_s_setprio(1);
#pragma unroll
    for (int gi = 0; gi < 2; ++gi)
#pragma unroll
      for (int m = 0; m < 4; ++m) {
        mfma_16x16x32_bf16(acc[2 + gi][4 + m], af1[m][0], wf23[gi][0]);
        mfma_16x16x32_bf16(acc[2 + gi][4 + m], af1[m][1], wf23[gi][1]);
      }
    __builtin_amdgcn_s_setprio(0);
    asm volatile("s_barrier" ::: "memory");
  }

  // ---- epilogue: gates + cell update (wave-local, all 4 gates in-wave) ----
  const int h = col0 + wn * 16 + lr16;
  const float bi  = bxi[h] + bhi[h];
  const float bff = bxf[h] + bhf[h];
  const float bc  = bxc[h] + bhc[h];
  const float bo  = bxo[h] + bho[h];
#pragma unroll
  for (int m = 0; m < 8; ++m) {
#pragma unroll
    for (int j = 0; j < 4; ++j) {
      const int r = row0 + wm * 128 + m * 16 + lq * 4 + j;
      const size_t o = (size_t)r * H_DIM + h;
      const float ig = fast_sigmoid(acc[0][m][j] + bi);
      const float fg = fast_sigmoid(acc[1][m][j] + bff);
      const float gg = fast_tanh   (acc[2][m][j] + bc);
      const float og = fast_sigmoid(acc[3][m][j] + bo);
      const float c  = cx[o] * fg + ig * gg;
      cy[o] = c;
      hy[o] = og * fast_tanh(c);
    }
  }
#undef STAGE_A
#undef STAGE_W
}

extern "C" void kernel_launch(void* const* d_in, const int* in_sizes, int n_in,
                              void* d_out, int out_size, void* d_ws, size_t ws_size,
                              hipStream_t stream) {
  const float* x   = (const float*)d_in[0];
  const float* hx  = (const float*)d_in[1];
  const float* cx  = (const float*)d_in[2];
  const float* wxi = (const float*)d_in[4];  const float* bxi = (const float*)d_in[5];
  const float* wxf = (const float*)d_in[6];  const float* bxf = (const float*)d_in[7];
  const float* wxc = (const float*)d_in[8];  const float* bxc = (const float*)d_in[9];
  const float* wxo = (const float*)d_in[10]; const float* bxo = (const float*)d_in[11];
  const float* whi = (const float*)d_in[12]; const float* bhi = (const float*)d_in[13];
  const float* whf = (const float*)d_in[14]; const float* bhf = (const float*)d_in[15];
  const float* whc = (const float*)d_in[16]; const float* bhc = (const float*)d_in[17];
  const float* who = (const float*)d_in[18]; const float* bho = (const float*)d_in[19];

  __hip_bfloat16* Abf = (__hip_bfloat16*)d_ws;
  __hip_bfloat16* Wbf = (__hip_bfloat16*)((char*)d_ws + (size_t)B_DIM * K_DIM * 2);

  float* hy  = (float*)d_out;
  float* cyo = (float*)d_out + (size_t)B_DIM * H_DIM;

  pack_a_kernel<<<(B_DIM * K_DIM / 8) / 256, 256, 0, stream>>>(x, hx, Abf);
  pack_w_kernel<<<(4 * H_DIM * K_DIM / 8) / 256, 256, 0, stream>>>(
      wxi, wxf, wxc, wxo, whi, whf, whc, who, Wbf);

  lstm_gemm_kernel<<<dim3(512), 512, 0, stream>>>(
      Abf, Wbf, cx, bxi, bhi, bxf, bhf, bxc, bhc, bxo, bho, hy, cyo);
}